// Round 15
// baseline (132.739 us; speedup 1.0000x reference)
//
#include <hip/hip_runtime.h>
#include <hip/hip_bf16.h>
#include <math.h>

#define NNODES 50000
#define NEDGES 400000
// MUL0=16, MUL1=8, IN_DIM=40; w2 cols: w00 [0,256) w10 [256,320) w01 [320,448) w11 [448,576)
#define ALPHA0f    0.20412414523193154f   // sqrt(1/24) == ALPHA1*INV_SQRT3
#define INV_SQRT3f 0.57735026918962576f
#define TPROW      64                     // bf16 tp row padded to 64 elems = 128 B = 1 line

typedef short bf16x8 __attribute__((ext_vector_type(8)));
typedef float f32x4  __attribute__((ext_vector_type(4)));

__device__ __forceinline__ short f2bf(float x) {
    __hip_bfloat16 h = __float2bfloat16(x);
    return *reinterpret_cast<short*>(&h);
}
__device__ __forceinline__ float bf2f(unsigned short x) {
    return __uint_as_float(((unsigned)x) << 16);
}
__device__ __forceinline__ float softplus_f(float x) {
    return fmaxf(x, 0.0f) + __logf(1.0f + __expf(-fabsf(x)));
}

// Transposed MFMA: D = A*B, A = W^T tile (rows = weight cols), B = data^T (cols = edges).
// D-fragment: lane's col (lane&15) = ITS OWN EDGE; rows (lane>>4)*4+r = weight cols.
// Proven state (R13): C=zero + short-lived post-add (R8), ILP windows (R9), fp32 xs
// epilogue + bf16 writeout (R11), bias-via-MFMA (R13). R12 lesson: VGPR cap <110 => spill.
// R14 lesson: perm-scattered writeout fails replay determinism — dense edge-order only.
// MODE 0: atomic-scatter fallback. MODE 1: bf16 tp rows (cols 0..39 written; pad never read).
template<int MODE>
__global__ __launch_bounds__(512)
void tp_mfma_kernel(const float* __restrict__ node_attr,
                    const int*   __restrict__ edge_index,
                    const float* __restrict__ edge_attr,
                    const float* __restrict__ edge_sh,
                    const float* __restrict__ w1,
                    const float* __restrict__ b1,
                    const float* __restrict__ w2,
                    const float* __restrict__ b2,
                    unsigned short* __restrict__ tp_out, // MODE1
                    int*   __restrict__ counts_i,        // MODE1
                    float* __restrict__ summed,          // MODE0
                    float* __restrict__ counts)          // MODE0
{
    __shared__ short w2f[36 * 512];      // A-fragments of W2^T tiles (36 KB)
    __shared__ short w1f[2 * 512];
    __shared__ float b1s[32];
    __shared__ float b2s[576];
    __shared__ float xs[8][16][44];      // node rows [40] + sh [40..43]; reused as fp32 out tile
    __shared__ short hs[8][16][48];      // h rows (bf16), GEMM1 transpose only
    __shared__ int   dsts[8][16];

    const int tid = threadIdx.x;

    for (int i = tid; i < 36 * 512; i += 512) {
        int col = i % 576, k = i / 576;
        int t = col >> 4, lr = col & 15, lg = k >> 3, j = k & 7;
        w2f[((t * 64 + (lr | (lg << 4))) * 8) + j] = f2bf(w2[i]);
    }
    for (int i = tid; i < 1024; i += 512) {
        int col = i & 31, k = i >> 5;
        int t = col >> 4, lr = col & 15, lg = k >> 3, j = k & 7;
        w1f[((t * 64 + (lr | (lg << 4))) * 8) + j] = f2bf(w1[i]);
    }
    if (tid < 32) b1s[tid] = b1[tid];
    for (int i = tid; i < 576; i += 512) b2s[i] = b2[i];
    __syncthreads();

    const int wid  = tid >> 6, lane = tid & 63;
    const int lrow = lane & 15, lgrp = lane >> 4;
    const int upar = lgrp >> 1;

    const bf16x8 w1a0 = *reinterpret_cast<const bf16x8*>(&w1f[lane * 8]);
    const bf16x8 w1a1 = *reinterpret_cast<const bf16x8*>(&w1f[512 + lane * 8]);
    const f32x4 b1c0 = *reinterpret_cast<const f32x4*>(&b1s[lgrp * 4]);
    const f32x4 b1c1 = *reinterpret_cast<const f32x4*>(&b1s[16 + lgrp * 4]);
    const f32x4 zero = {0.f, 0.f, 0.f, 0.f};

    // ---- bias A-fragments (registers, once per thread): A[w=lrow][u=lgrp*8+j] ----
    bf16x8 b2a00, b2a01;
    #pragma unroll
    for (int j = 0; j < 8; ++j) {
        int u = lgrp * 8 + j;
        b2a00[j] = (u < 16) ? f2bf(b2[u * 16 + lrow]) : (short)0;
        b2a01[j] = (u < 16 && lrow < 8) ? f2bf(b2[320 + u * 8 + lrow]) : (short)0;
    }

    for (int g = blockIdx.x; g < NEDGES / 128; g += gridDim.x) {
        const int e0 = g * 128 + wid * 16;

        if (lane < 16) {
            int d = edge_index[NEDGES + e0 + lane];
            dsts[wid][lane] = d;
            float4 sh = *(const float4*)(edge_sh + (size_t)(e0 + lane) * 4);
            xs[wid][lane][40] = sh.x; xs[wid][lane][41] = sh.y;
            xs[wid][lane][42] = sh.z; xs[wid][lane][43] = sh.w;
        }
        #pragma unroll
        for (int it = 0; it < 3; ++it) {
            int idx = it * 64 + lane;
            if (idx < 160) {
                int ed = idx / 10, part = idx % 10;
                int d = dsts[wid][ed];
                float4 v = *(const float4*)(node_attr + (size_t)d * 40 + part * 4);
                *(float4*)&xs[wid][ed][part * 4] = v;
            }
        }

        // ---- GEMM1 (transposed): D1 = W1^T * EA^T + b1 ; lane col = its own edge ----
        const float4* ear = (const float4*)(edge_attr + (size_t)(e0 + lrow) * 32 + lgrp * 8);
        float4 ea0 = ear[0], ea1 = ear[1];
        bf16x8 bfrag;
        bfrag[0] = f2bf(ea0.x); bfrag[1] = f2bf(ea0.y); bfrag[2] = f2bf(ea0.z); bfrag[3] = f2bf(ea0.w);
        bfrag[4] = f2bf(ea1.x); bfrag[5] = f2bf(ea1.y); bfrag[6] = f2bf(ea1.z); bfrag[7] = f2bf(ea1.w);
        f32x4 c0 = __builtin_amdgcn_mfma_f32_16x16x32_bf16(w1a0, bfrag, b1c0, 0, 0, 0);
        f32x4 c1 = __builtin_amdgcn_mfma_f32_16x16x32_bf16(w1a1, bfrag, b1c1, 0, 0, 0);
        {
            short4 p0, p1;
            p0.x = f2bf(softplus_f(c0[0])); p0.y = f2bf(softplus_f(c0[1]));
            p0.z = f2bf(softplus_f(c0[2])); p0.w = f2bf(softplus_f(c0[3]));
            p1.x = f2bf(softplus_f(c1[0])); p1.y = f2bf(softplus_f(c1[1]));
            p1.z = f2bf(softplus_f(c1[2])); p1.w = f2bf(softplus_f(c1[3]));
            *(short4*)&hs[wid][lrow][lgrp * 4]      = p0;
            *(short4*)&hs[wid][lrow][16 + lgrp * 4] = p1;
        }
        const bf16x8 hfrag = *reinterpret_cast<const bf16x8*>(&hs[wid][lrow][lgrp * 8]);

        const float y0  = xs[wid][lrow][40];
        const float y1x = xs[wid][lrow][41];
        const float y1y = xs[wid][lrow][42];
        const float y1z = xs[wid][lrow][43];

        // ---- s0 B-fragment (this edge's s0 along K; lgrp>=2 lanes are the K zero pad) ----
        bf16x8 s0f;
        {
            f32x4 sA = *(const f32x4*)&xs[wid][lrow][(lgrp & 1) * 8];
            f32x4 sB = *(const f32x4*)&xs[wid][lrow][(lgrp & 1) * 8 + 4];
            bool live = (lgrp < 2);
            #pragma unroll
            for (int j = 0; j < 4; ++j) s0f[j]     = live ? f2bf(sA[j]) : (short)0;
            #pragma unroll
            for (int j = 0; j < 4; ++j) s0f[4 + j] = live ? f2bf(sB[j]) : (short)0;
        }
        // bias MFMAs: D[w=lgrp*4+r][edge=lrow] = sum_u b2[u,w] * s0[u]
        f32x4 acc0 = __builtin_amdgcn_mfma_f32_16x16x32_bf16(b2a00, s0f, zero, 0, 0, 0);
        acc0 *= y0;
        f32x4 r01  = __builtin_amdgcn_mfma_f32_16x16x32_bf16(b2a01, s0f, zero, 0, 0, 0);
        f32x4 am0 = zero, am1 = zero, am2 = zero;

        // ---- w00 (tiles 0..15): u=t, w=lgrp*4+r; bias handled above ----
        #pragma unroll 1
        for (int t0 = 0; t0 < 16; t0 += 4) {
            f32x4 F4 = *(const f32x4*)&xs[wid][lrow][t0];
            #pragma unroll
            for (int q = 0; q < 4; ++q) {
                bf16x8 wa = *reinterpret_cast<const bf16x8*>(&w2f[((t0 + q) * 64 + lane) * 8]);
                f32x4 wv = __builtin_amdgcn_mfma_f32_16x16x32_bf16(wa, hfrag, zero, 0, 0, 0);
                acc0 += wv * (F4[q] * y0);
            }
        }
        // ---- w10 (tiles 16..19): u = 2*tt+upar, w = (lgrp&1)*4+r ----
        #pragma unroll 4
        for (int tt = 0; tt < 4; ++tt) {
            int t = 16 + tt;
            bf16x8 wa = *reinterpret_cast<const bf16x8*>(&w2f[(t * 64 + lane) * 8]);
            f32x4 wv = __builtin_amdgcn_mfma_f32_16x16x32_bf16(wa, hfrag, zero, 0, 0, 0);
            f32x4 b2c = *reinterpret_cast<const f32x4*>(&b2s[t * 16 + lgrp * 4]);
            int u = 2 * tt + upar;
            f32x4 wb = wv + b2c;
            float f0 = y0 * xs[wid][lrow][16 + u * 3 + 0];
            float f1 = y0 * xs[wid][lrow][16 + u * 3 + 1];
            float f2 = y0 * xs[wid][lrow][16 + u * 3 + 2];
            am0 += wb * f0; am1 += wb * f1; am2 += wb * f2;
        }
        // ---- w01 (tiles 20..27): u = 2*tt+upar; bias handled by bias01 ----
        #pragma unroll 4
        for (int tt = 0; tt < 8; ++tt) {
            int t = 20 + tt;
            bf16x8 wa = *reinterpret_cast<const bf16x8*>(&w2f[(t * 64 + lane) * 8]);
            f32x4 wv = __builtin_amdgcn_mfma_f32_16x16x32_bf16(wa, hfrag, zero, 0, 0, 0);
            int u = 2 * tt + upar;
            float s = xs[wid][lrow][u];
            r01 += wv * s;
        }
        // ---- w11 (tiles 28..35): u = tt, w = lgrp*4+r; vectorized v1 reads ----
        #pragma unroll 1
        for (int tt0 = 0; tt0 < 8; tt0 += 4) {
            f32x4 vA = *(const f32x4*)&xs[wid][lrow][16 + 3 * tt0];
            f32x4 vB = *(const f32x4*)&xs[wid][lrow][16 + 3 * tt0 + 4];
            f32x4 vC = *(const f32x4*)&xs[wid][lrow][16 + 3 * tt0 + 8];
            float e[12] = {vA[0], vA[1], vA[2], vA[3], vB[0], vB[1],
                           vB[2], vB[3], vC[0], vC[1], vC[2], vC[3]};
            #pragma unroll
            for (int q = 0; q < 4; ++q) {
                int t = 28 + tt0 + q;
                bf16x8 wa = *reinterpret_cast<const bf16x8*>(&w2f[(t * 64 + lane) * 8]);
                f32x4 wv = __builtin_amdgcn_mfma_f32_16x16x32_bf16(wa, hfrag, zero, 0, 0, 0);
                f32x4 b2c = *reinterpret_cast<const f32x4*>(&b2s[t * 16 + lgrp * 4]);
                float bu = INV_SQRT3f * (e[3 * q] * y1x + e[3 * q + 1] * y1y + e[3 * q + 2] * y1z);
                acc0 += (wv + b2c) * bu;
            }
        }

        // ---- combine u-parities (lanes l, l^32 share w) ----
        #pragma unroll
        for (int r = 0; r < 4; ++r) {
            am0[r] += __shfl_xor(am0[r], 32);
            am1[r] += __shfl_xor(am1[r], 32);
            am2[r] += __shfl_xor(am2[r], 32);
            r01[r] += __shfl_xor(r01[r], 32);
        }

        if (MODE == 1) {
            // ---- epilogue via fp32 xs tile (stride 44: conflict-free) ----
            #pragma unroll
            for (int r = 0; r < 4; ++r)
                xs[wid][lrow][lgrp * 4 + r] = ALPHA0f * acc0[r];
            if (lgrp < 2) {
                #pragma unroll
                for (int r = 0; r < 4; ++r) {
                    xs[wid][lrow][16 + lgrp * 12 + r * 3 + 0] = ALPHA0f * (am0[r] + y1x * r01[r]);
                    xs[wid][lrow][16 + lgrp * 12 + r * 3 + 1] = ALPHA0f * (am1[r] + y1y * r01[r]);
                    xs[wid][lrow][16 + lgrp * 12 + r * 3 + 2] = ALPHA0f * (am2[r] + y1z * r01[r]);
                }
            }
            // wave-internal LDS RAW: compiler inserts lgkmcnt wait; per-wave tile, no barrier
            // ---- writeout: cvt fp32->bf16, rows at 128-B stride; pad cols 40..63 never read ----
            #pragma unroll
            for (int it = 0; it < 3; ++it) {
                int idx = it * 64 + lane;
                if (idx < 160) {
                    int ed = idx / 10, part = idx % 10;
                    float4 v = *(float4*)&xs[wid][ed][part * 4];
                    short4 s;
                    s.x = f2bf(v.x); s.y = f2bf(v.y); s.z = f2bf(v.z); s.w = f2bf(v.w);
                    *(short4*)(tp_out + (size_t)(e0 + ed) * TPROW + part * 4) = s;
                }
            }
            if (lgrp == 0) atomicAdd(&counts_i[edge_index[e0 + lrow]], 1);
        } else {
            const int src = edge_index[e0 + lrow];
            float* row = summed + (size_t)src * 40;
            #pragma unroll
            for (int r = 0; r < 4; ++r)
                atomicAdd(row + lgrp * 4 + r, ALPHA0f * acc0[r]);
            if (lgrp < 2) {
                float* r1 = row + 16 + lgrp * 12;
                #pragma unroll
                for (int r = 0; r < 4; ++r) {
                    atomicAdd(r1 + r * 3 + 0, ALPHA0f * (am0[r] + y1x * r01[r]));
                    atomicAdd(r1 + r * 3 + 1, ALPHA0f * (am1[r] + y1y * r01[r]));
                    atomicAdd(r1 + r * 3 + 2, ALPHA0f * (am2[r] + y1z * r01[r]));
                }
            }
            if (lgrp == 0) atomicAdd(&counts[src], 1.0f);
        }
    }
}

extern "C" __global__ __launch_bounds__(256)
void scanA_kernel(const int* __restrict__ counts_i, int* __restrict__ offsets,
                  int* __restrict__ bsums)
{
    __shared__ int s[256];
    int t = threadIdx.x, id = blockIdx.x * 256 + t;
    int c = (id < NNODES) ? counts_i[id] : 0;
    s[t] = c; __syncthreads();
    #pragma unroll
    for (int off = 1; off < 256; off <<= 1) {
        int v = (t >= off) ? s[t - off] : 0;
        __syncthreads();
        s[t] += v;
        __syncthreads();
    }
    if (id < NNODES) offsets[id] = s[t] - c;
    if (t == 255) bsums[blockIdx.x] = s[255];
}

extern "C" __global__ __launch_bounds__(256)
void scanB_kernel(int* __restrict__ bsums, int nblocks)
{
    __shared__ int s[256];
    int t = threadIdx.x;
    int c = (t < nblocks) ? bsums[t] : 0;
    s[t] = c; __syncthreads();
    #pragma unroll
    for (int off = 1; off < 256; off <<= 1) {
        int v = (t >= off) ? s[t - off] : 0;
        __syncthreads();
        s[t] += v;
        __syncthreads();
    }
    if (t < nblocks) bsums[t] = s[t] - c;
}

extern "C" __global__ __launch_bounds__(256)
void scanC_kernel(int* __restrict__ offsets, const int* __restrict__ bsums,
                  int* __restrict__ cursor)
{
    int id = blockIdx.x * 256 + threadIdx.x;
    if (id < NNODES) {
        int o = offsets[id] + bsums[id >> 8];
        offsets[id] = o;
        cursor[id] = o;
    }
}

extern "C" __global__ __launch_bounds__(256)
void scatter_kernel(const int* __restrict__ edge_index, int* __restrict__ cursor,
                    int* __restrict__ csr)
{
    int e = blockIdx.x * 256 + threadIdx.x;
    if (e < NEDGES) {
        int src = edge_index[e];
        int pos = atomicAdd(&cursor[src], 1);
        csr[pos] = e;
    }
}

// segmented mean + residual; one wave per node; tp rows = single 128-B lines (bf16)
extern "C" __global__ __launch_bounds__(256)
void gather_kernel(const unsigned short* __restrict__ tp, const int* __restrict__ offsets,
                   const int* __restrict__ csr, const float* __restrict__ node_attr,
                   float* __restrict__ out)
{
    int gw = (blockIdx.x * 256 + threadIdx.x) >> 6;
    int lane = threadIdx.x & 63;
    int nwaves = (gridDim.x * 256) >> 6;
    for (int n = gw; n < NNODES; n += nwaves) {
        int start = offsets[n];
        int end = (n + 1 < NNODES) ? offsets[n + 1] : NEDGES;
        float a0 = 0.f, a1 = 0.f, a2 = 0.f, a3 = 0.f;
        int i = start;
        for (; i + 8 <= end; i += 8) {
            int i0 = csr[i],     i1 = csr[i + 1], i2 = csr[i + 2], i3 = csr[i + 3];
            int i4 = csr[i + 4], i5 = csr[i + 5], i6 = csr[i + 6], i7 = csr[i + 7];
            if (lane < 40) {
                a0 += bf2f(tp[(size_t)i0 * TPROW + lane]);
                a1 += bf2f(tp[(size_t)i1 * TPROW + lane]);
                a2 += bf2f(tp[(size_t)i2 * TPROW + lane]);
                a3 += bf2f(tp[(size_t)i3 * TPROW + lane]);
                a0 += bf2f(tp[(size_t)i4 * TPROW + lane]);
                a1 += bf2f(tp[(size_t)i5 * TPROW + lane]);
                a2 += bf2f(tp[(size_t)i6 * TPROW + lane]);
                a3 += bf2f(tp[(size_t)i7 * TPROW + lane]);
            }
        }
        for (; i + 2 <= end; i += 2) {
            int i0 = csr[i], i1 = csr[i + 1];
            if (lane < 40) {
                a0 += bf2f(tp[(size_t)i0 * TPROW + lane]);
                a1 += bf2f(tp[(size_t)i1 * TPROW + lane]);
            }
        }
        if (i < end) {
            int i0 = csr[i];
            if (lane < 40) a0 += bf2f(tp[(size_t)i0 * TPROW + lane]);
        }
        if (lane < 40) {
            float deg = (float)(end - start);
            out[(size_t)n * 40 + lane] =
                ((a0 + a1) + (a2 + a3)) / fmaxf(deg, 1.0f) + node_attr[(size_t)n * 40 + lane];
        }
    }
}

extern "C" __global__ __launch_bounds__(256)
void finalize_kernel(const float* __restrict__ summed,
                     const float* __restrict__ counts,
                     const float* __restrict__ node_attr,
                     float* __restrict__ out)
{
    int idx = blockIdx.x * 256 + threadIdx.x;
    if (idx < NNODES * 40) {
        int n = idx / 40;
        float c = fmaxf(counts[n], 1.0f);
        out[idx] = summed[idx] / c + node_attr[idx];
    }
}

extern "C" void kernel_launch(void* const* d_in, const int* in_sizes, int n_in,
                              void* d_out, int out_size, void* d_ws, size_t ws_size,
                              hipStream_t stream)
{
    const float* node_attr  = (const float*)d_in[0];
    const int*   edge_index = (const int*)  d_in[1];
    const float* edge_attr  = (const float*)d_in[2];
    const float* edge_sh    = (const float*)d_in[3];
    const float* w1 = (const float*)d_in[4];
    const float* b1 = (const float*)d_in[5];
    const float* w2 = (const float*)d_in[6];
    const float* b2 = (const float*)d_in[7];
    float* out = (float*)d_out;

    const int SCAN_BLOCKS = (NNODES + 255) / 256;   // 196
    const int EDGE_BLOCKS = (NEDGES + 255) / 256;   // 1563
    const size_t NEED = (size_t)NEDGES * TPROW * 2 +
                        ((size_t)3 * NNODES + NEDGES + 256) * 4;

    if (ws_size >= NEED) {
        unsigned short* tp = (unsigned short*)d_ws;          // NEDGES*64 bf16 (128-B rows)
        int* counts_i = (int*)(tp + (size_t)NEDGES * TPROW); // NNODES
        int* offsets  = counts_i + NNODES;                   // NNODES
        int* cursor   = offsets + NNODES;                    // NNODES
        int* csr      = cursor + NNODES;                     // NEDGES
        int* bsums    = csr + NEDGES;                        // 256

        hipMemsetAsync(counts_i, 0, (size_t)NNODES * 4, stream);

        hipLaunchKernelGGL((tp_mfma_kernel<1>), dim3(512), dim3(512), 0, stream,
                           node_attr, edge_index, edge_attr, edge_sh, w1, b1, w2, b2,
                           tp, counts_i, (float*)nullptr, (float*)nullptr);

        hipLaunchKernelGGL(scanA_kernel, dim3(SCAN_BLOCKS), dim3(256), 0, stream,
                           counts_i, offsets, bsums);
        hipLaunchKernelGGL(scanB_kernel, dim3(1), dim3(256), 0, stream,
                           bsums, SCAN_BLOCKS);
        hipLaunchKernelGGL(scanC_kernel, dim3(SCAN_BLOCKS), dim3(256), 0, stream,
                           offsets, bsums, cursor);
        hipLaunchKernelGGL(scatter_kernel, dim3(EDGE_BLOCKS), dim3(256), 0, stream,
                           edge_index, cursor, csr);
        hipLaunchKernelGGL(gather_kernel, dim3(2048), dim3(256), 0, stream,
                           tp, offsets, csr, node_attr, out);
    } else {
        float* summed = (float*)d_ws;
        float* counts = summed + (size_t)NNODES * 40;
        hipMemsetAsync(d_ws, 0, (size_t)(NNODES * 40 + NNODES) * sizeof(float), stream);
        hipLaunchKernelGGL((tp_mfma_kernel<0>), dim3(512), dim3(512), 0, stream,
                           node_attr, edge_index, edge_attr, edge_sh, w1, b1, w2, b2,
                           (unsigned short*)nullptr, (int*)nullptr, summed, counts);
        int fblk = (NNODES * 40 + 255) / 256;
        hipLaunchKernelGGL(finalize_kernel, dim3(fblk), dim3(256), 0, stream,
                           summed, counts, node_attr, out);
    }
}

// Round 16
// 116.781 us; speedup vs baseline: 1.1366x; 1.1366x over previous
//
#include <hip/hip_runtime.h>
#include <hip/hip_bf16.h>
#include <math.h>

#define NNODES 50000
#define NEDGES 400000
// MUL0=16, MUL1=8, IN_DIM=40; w2 cols: w00 [0,256) w10 [256,320) w01 [320,448) w11 [448,576)
#define ALPHA0f    0.20412414523193154f   // sqrt(1/24) == ALPHA1*INV_SQRT3
#define INV_SQRT3f 0.57735026918962576f
#define TPROW      64                     // bf16 tp row padded to 64 elems = 128 B = 1 line

typedef short bf16x8 __attribute__((ext_vector_type(8)));
typedef float f32x4  __attribute__((ext_vector_type(4)));
typedef float f32x16 __attribute__((ext_vector_type(16)));
typedef unsigned int u32x4 __attribute__((ext_vector_type(4)));

__device__ __forceinline__ short f2bf(float x) {
    __hip_bfloat16 h = __float2bfloat16(x);
    return *reinterpret_cast<short*>(&h);
}
__device__ __forceinline__ unsigned f2bfu(float x) {
    __hip_bfloat16 h = __float2bfloat16(x);
    return (unsigned)*reinterpret_cast<unsigned short*>(&h);
}
__device__ __forceinline__ float bf2f(unsigned short x) {
    return __uint_as_float(((unsigned)x) << 16);
}
__device__ __forceinline__ unsigned pack2(float a, float b) {
    return f2bfu(a) | (f2bfu(b) << 16);
}
__device__ __forceinline__ float softplus_f(float x) {
    return fmaxf(x, 0.0f) + __logf(1.0f + __expf(-fabsf(x)));
}

// R16: 32x32x16 MFMA restructure. One wave = 32 edges; lane owns edge (lane&31).
// D layout (verified m74/m101): col=lane&31, row=(reg&3)+8*(reg>>2)+4*(lane>>5).
// A/B layout (extrapolated from verified 16x16 pattern): row/col = lane&31,
// k = (lane>>5)*8 + j. K=32 via two chained MFMAs (kh=0,1).
// Both u-halves of each output w land in ONE lane -> no shfl reduction, direct stores.
// Bias for w00+w01 via one packed bias-MFMA (A rows 0-15: b2[u*16+row]; 16-23:
// b2[320+u*8+row-16]; 24-31: 0). b2c for w10/w11 is wave-uniform (broadcast LDS).
// Kept lessons: C-chaining not LDS C-in (R8), bounded unroll (R9/R12), dense
// edge-order bf16 tp rows (R11/R14).
template<int MODE>
__global__ __launch_bounds__(512)
void tp_mfma_kernel(const float* __restrict__ node_attr,
                    const int*   __restrict__ edge_index,
                    const float* __restrict__ edge_attr,
                    const float* __restrict__ edge_sh,
                    const float* __restrict__ w1,
                    const float* __restrict__ b1,
                    const float* __restrict__ w2,
                    const float* __restrict__ b2,
                    unsigned short* __restrict__ tp_out, // MODE1
                    int*   __restrict__ counts_i,        // MODE1
                    float* __restrict__ summed,          // MODE0
                    float* __restrict__ counts)          // MODE0
{
    __shared__ short w2f[18 * 2 * 512];          // A-fragments: [tile][kh][lane][8] (36.9 KB)
    __shared__ float b1s[32];
    __shared__ float b2s[576];
    __shared__ unsigned short xsb[8][32][44];    // bf16 node rows [40] per wave (22 KB)

    const int tid = threadIdx.x;

    for (int i = tid; i < 18432; i += 512) {
        int col = i % 576, k = i / 576;          // w2[k][col], coalesced
        int t = col >> 5, lr = col & 31, kh = k >> 4, lg = (k >> 3) & 1, j = k & 7;
        w2f[(((t * 2 + kh) * 64) + (lr | (lg << 5))) * 8 + j] = f2bf(w2[i]);
    }
    if (tid < 32) b1s[tid] = b1[tid];
    for (int i = tid; i < 576; i += 512) b2s[i] = b2[i];
    __syncthreads();

    const int wid = tid >> 6, lane = tid & 63;
    const int le = lane & 31, s = lane >> 5;

    // ---- persistent fragments ----
    bf16x8 w1a0, w1a1;                           // GEMM1 A (W1^T), kh=0/1
    #pragma unroll
    for (int j = 0; j < 8; ++j) {
        w1a0[j] = f2bf(w1[(s * 8 + j) * 32 + le]);
        w1a1[j] = f2bf(w1[(16 + s * 8 + j) * 32 + le]);
    }
    bf16x8 ab;                                   // packed bias A (w00 rows 0-15, w01 rows 16-23)
    #pragma unroll
    for (int j = 0; j < 8; ++j) {
        int u = s * 8 + j;
        float v = (le < 16) ? b2[u * 16 + le]
                : (le < 24) ? b2[320 + u * 8 + (le - 16)] : 0.0f;
        ab[j] = f2bf(v);
    }
    f32x16 zero16;
    #pragma unroll
    for (int i = 0; i < 16; ++i) zero16[i] = 0.0f;

    const int NGROUPS = (NEDGES + 255) / 256;    // 1563 (last group: 128 edges, waves 0-3)

    for (int g = blockIdx.x; g < NGROUPS; g += gridDim.x) {
        const int e0 = g * 256 + wid * 32;
        if (e0 >= NEDGES) continue;              // tail waves idle (no barriers in loop)

        // ---- stage 32 node rows as bf16 into xsb ----
        int dval = (lane < 32) ? edge_index[NEDGES + e0 + lane] : 0;
        #pragma unroll
        for (int it = 0; it < 5; ++it) {
            int c = it * 64 + lane;              // 0..319 = 32 rows x 10 float4-parts
            int row = c / 10, part = c % 10;
            int d = __shfl(dval, row);
            float4 v = *(const float4*)(node_attr + (size_t)d * 40 + part * 4);
            short4 sx;
            sx.x = f2bf(v.x); sx.y = f2bf(v.y); sx.z = f2bf(v.z); sx.w = f2bf(v.w);
            *(short4*)&xsb[wid][row][part * 4] = sx;
        }
        const float4 sh = *(const float4*)(edge_sh + (size_t)(e0 + le) * 4);
        const float y0 = sh.x, y1x = sh.y, y1y = sh.z, y1z = sh.w;
        const int srcv = edge_index[e0 + le];

        // ---- GEMM1: D1[j][e] = W1^T * EA^T (+b1, softplus) ----
        const float* ear = edge_attr + (size_t)(e0 + le) * 32;
        bf16x8 bf1a, bf1b;
        {
            float4 a0 = *(const float4*)(ear + s * 8);
            float4 a1 = *(const float4*)(ear + s * 8 + 4);
            float4 b0 = *(const float4*)(ear + 16 + s * 8);
            float4 b1v = *(const float4*)(ear + 16 + s * 8 + 4);
            bf1a[0]=f2bf(a0.x); bf1a[1]=f2bf(a0.y); bf1a[2]=f2bf(a0.z); bf1a[3]=f2bf(a0.w);
            bf1a[4]=f2bf(a1.x); bf1a[5]=f2bf(a1.y); bf1a[6]=f2bf(a1.z); bf1a[7]=f2bf(a1.w);
            bf1b[0]=f2bf(b0.x); bf1b[1]=f2bf(b0.y); bf1b[2]=f2bf(b0.z); bf1b[3]=f2bf(b0.w);
            bf1b[4]=f2bf(b1v.x); bf1b[5]=f2bf(b1v.y); bf1b[6]=f2bf(b1v.z); bf1b[7]=f2bf(b1v.w);
        }
        f32x16 c1 = __builtin_amdgcn_mfma_f32_32x32x16_bf16(w1a0, bf1a, zero16, 0, 0, 0);
        c1 = __builtin_amdgcn_mfma_f32_32x32x16_bf16(w1a1, bf1b, c1, 0, 0, 0);

        // softplus + pack pairs: P[q] covers regs (2q,2q+1); j(r) = (r&3)+8*(r>>2)+4s
        unsigned P[8];
        #pragma unroll
        for (int q = 0; q < 8; ++q) {
            int r0 = 2 * q, r1 = 2 * q + 1;
            int j0 = (r0 & 3) + 8 * (r0 >> 2) + 4 * s;
            int j1 = (r1 & 3) + 8 * (r1 >> 2) + 4 * s;
            P[q] = pack2(softplus_f(c1[r0] + b1s[j0]), softplus_f(c1[r1] + b1s[j1]));
        }
        // exchange with partner lane (l^32) to build contiguous-k B2 fragments
        unsigned x0 = (unsigned)__shfl_xor((int)(s ? P[0] : P[2]), 32);
        unsigned x1 = (unsigned)__shfl_xor((int)(s ? P[1] : P[3]), 32);
        unsigned x2 = (unsigned)__shfl_xor((int)(s ? P[4] : P[6]), 32);
        unsigned x3 = (unsigned)__shfl_xor((int)(s ? P[5] : P[7]), 32);
        u32x4 hw0, hw1;
        hw0[0] = s ? x0 : P[0];  hw0[1] = s ? x1 : P[1];
        hw0[2] = s ? P[2] : x0;  hw0[3] = s ? P[3] : x1;
        hw1[0] = s ? x2 : P[4];  hw1[1] = s ? x3 : P[5];
        hw1[2] = s ? P[6] : x2;  hw1[3] = s ? P[7] : x3;
        const bf16x8 hf0 = *reinterpret_cast<bf16x8*>(&hw0);   // k = s*8..+7
        const bf16x8 hf1 = *reinterpret_cast<bf16x8*>(&hw1);   // k = 16+s*8..+7

        // ---- bias MFMA: D[row][e] = sum_u ab[row][u] * s0[e][u] ----
        bf16x8 s0f;
        {
            short4 a = *(const short4*)&xsb[wid][le][s * 8];
            short4 b = *(const short4*)&xsb[wid][le][s * 8 + 4];
            s0f[0]=a.x; s0f[1]=a.y; s0f[2]=a.z; s0f[3]=a.w;
            s0f[4]=b.x; s0f[5]=b.y; s0f[6]=b.z; s0f[7]=b.w;
        }
        f32x16 dbias = __builtin_amdgcn_mfma_f32_32x32x16_bf16(ab, s0f, zero16, 0, 0, 0);

        float acc0[8], r01[4], am0[4], am1[4], am2[4];
        #pragma unroll
        for (int i = 0; i < 8; ++i) acc0[i] = dbias[i] * y0;       // w00 bias
        #pragma unroll
        for (int i = 0; i < 4; ++i) { r01[i] = dbias[8 + i];       // w01 bias
                                      am0[i] = 0.f; am1[i] = 0.f; am2[i] = 0.f; }

        // ---- w00: tiles 0..7 (cols 32t+row; u = 2t + (r>=8); slot = r&7) ----
        #pragma unroll 2
        for (int t = 0; t < 8; ++t) {
            bf16x8 wa0 = *reinterpret_cast<const bf16x8*>(&w2f[((t * 2 + 0) * 64 + lane) * 8]);
            bf16x8 wa1 = *reinterpret_cast<const bf16x8*>(&w2f[((t * 2 + 1) * 64 + lane) * 8]);
            f32x16 wv = __builtin_amdgcn_mfma_f32_32x32x16_bf16(wa0, hf0, zero16, 0, 0, 0);
            wv = __builtin_amdgcn_mfma_f32_32x32x16_bf16(wa1, hf1, wv, 0, 0, 0);
            float F0 = bf2f(xsb[wid][le][2 * t])     * y0;
            float F1 = bf2f(xsb[wid][le][2 * t + 1]) * y0;
            #pragma unroll
            for (int r = 0; r < 8; ++r) acc0[r] += wv[r] * F0;
            #pragma unroll
            for (int r = 0; r < 8; ++r) acc0[r] += wv[8 + r] * F1;
        }
        // ---- w10: tiles 8..9 (cols 256+tt*32+row; u = 4tt+q; w' = k) ----
        #pragma unroll 1
        for (int tt = 0; tt < 2; ++tt) {
            int tb = (8 + tt) * 2;
            bf16x8 wa0 = *reinterpret_cast<const bf16x8*>(&w2f[((tb + 0) * 64 + lane) * 8]);
            bf16x8 wa1 = *reinterpret_cast<const bf16x8*>(&w2f[((tb + 1) * 64 + lane) * 8]);
            f32x16 wv = __builtin_amdgcn_mfma_f32_32x32x16_bf16(wa0, hf0, zero16, 0, 0, 0);
            wv = __builtin_amdgcn_mfma_f32_32x32x16_bf16(wa1, hf1, wv, 0, 0, 0);
            #pragma unroll
            for (int q = 0; q < 4; ++q) {
                int u = 4 * tt + q;
                float f0 = y0 * bf2f(xsb[wid][le][16 + u * 3 + 0]);
                float f1 = y0 * bf2f(xsb[wid][le][16 + u * 3 + 1]);
                float f2 = y0 * bf2f(xsb[wid][le][16 + u * 3 + 2]);
                f32x4 b2q = *(const f32x4*)&b2s[256 + tt * 32 + 8 * q + 4 * s];
                #pragma unroll
                for (int k = 0; k < 4; ++k) {
                    float wb = wv[4 * q + k] + b2q[k];
                    am0[k] += wb * f0; am1[k] += wb * f1; am2[k] += wb * f2;
                }
            }
        }
        // ---- w01: tiles 10..13 (cols 320+tt*32+row; u = 4tt+q; bias via dbias) ----
        #pragma unroll 1
        for (int tt = 0; tt < 4; ++tt) {
            int tb = (10 + tt) * 2;
            bf16x8 wa0 = *reinterpret_cast<const bf16x8*>(&w2f[((tb + 0) * 64 + lane) * 8]);
            bf16x8 wa1 = *reinterpret_cast<const bf16x8*>(&w2f[((tb + 1) * 64 + lane) * 8]);
            f32x16 wv = __builtin_amdgcn_mfma_f32_32x32x16_bf16(wa0, hf0, zero16, 0, 0, 0);
            wv = __builtin_amdgcn_mfma_f32_32x32x16_bf16(wa1, hf1, wv, 0, 0, 0);
            #pragma unroll
            for (int q = 0; q < 4; ++q) {
                float su = bf2f(xsb[wid][le][4 * tt + q]);
                #pragma unroll
                for (int k = 0; k < 4; ++k) r01[k] += wv[4 * q + k] * su;
            }
        }
        // ---- w11: tiles 14..17 (cols 448+tt*32+row; u = 2tt+(r>=8); slot = r&7) ----
        #pragma unroll 1
        for (int tt = 0; tt < 4; ++tt) {
            int tb = (14 + tt) * 2;
            bf16x8 wa0 = *reinterpret_cast<const bf16x8*>(&w2f[((tb + 0) * 64 + lane) * 8]);
            bf16x8 wa1 = *reinterpret_cast<const bf16x8*>(&w2f[((tb + 1) * 64 + lane) * 8]);
            f32x16 wv = __builtin_amdgcn_mfma_f32_32x32x16_bf16(wa0, hf0, zero16, 0, 0, 0);
            wv = __builtin_amdgcn_mfma_f32_32x32x16_bf16(wa1, hf1, wv, 0, 0, 0);
            int u0 = 2 * tt, u1 = 2 * tt + 1;
            float bu0 = INV_SQRT3f * (bf2f(xsb[wid][le][16 + u0 * 3 + 0]) * y1x +
                                      bf2f(xsb[wid][le][16 + u0 * 3 + 1]) * y1y +
                                      bf2f(xsb[wid][le][16 + u0 * 3 + 2]) * y1z);
            float bu1 = INV_SQRT3f * (bf2f(xsb[wid][le][16 + u1 * 3 + 0]) * y1x +
                                      bf2f(xsb[wid][le][16 + u1 * 3 + 1]) * y1y +
                                      bf2f(xsb[wid][le][16 + u1 * 3 + 2]) * y1z);
            f32x4 bq0 = *(const f32x4*)&b2s[448 + tt * 32 + 4 * s];
            f32x4 bq1 = *(const f32x4*)&b2s[448 + tt * 32 + 8 + 4 * s];
            f32x4 bq2 = *(const f32x4*)&b2s[448 + tt * 32 + 16 + 4 * s];
            f32x4 bq3 = *(const f32x4*)&b2s[448 + tt * 32 + 24 + 4 * s];
            #pragma unroll
            for (int k = 0; k < 4; ++k) {
                acc0[k]     += (wv[k]      + bq0[k]) * bu0;
                acc0[4 + k] += (wv[4 + k]  + bq1[k]) * bu0;
                acc0[k]     += (wv[8 + k]  + bq2[k]) * bu1;
                acc0[4 + k] += (wv[12 + k] + bq3[k]) * bu1;
            }
        }

        // ---- epilogue: lane owns edge e0+le; global w for slot i: {0-3}[i]+4s (i<4),
        //      {8-11}[i-4]+4s (i>=4); out1 w = w'+4s, w' = 0..3 ----
        float o1[12];
        #pragma unroll
        for (int w = 0; w < 4; ++w) {
            o1[w * 3 + 0] = ALPHA0f * (am0[w] + y1x * r01[w]);
            o1[w * 3 + 1] = ALPHA0f * (am1[w] + y1y * r01[w]);
            o1[w * 3 + 2] = ALPHA0f * (am2[w] + y1z * r01[w]);
        }
        if (MODE == 1) {
            unsigned short* rowp = tp_out + (size_t)(e0 + le) * TPROW;
            short4 sa, sb;
            sa.x = f2bf(ALPHA0f * acc0[0]); sa.y = f2bf(ALPHA0f * acc0[1]);
            sa.z = f2bf(ALPHA0f * acc0[2]); sa.w = f2bf(ALPHA0f * acc0[3]);
            sb.x = f2bf(ALPHA0f * acc0[4]); sb.y = f2bf(ALPHA0f * acc0[5]);
            sb.z = f2bf(ALPHA0f * acc0[6]); sb.w = f2bf(ALPHA0f * acc0[7]);
            *(short4*)(rowp + 4 * s)     = sa;    // w {0-3}+4s
            *(short4*)(rowp + 8 + 4 * s) = sb;    // w {8-11}+4s
            #pragma unroll
            for (int q = 0; q < 3; ++q) {
                short4 sq;
                sq.x = f2bf(o1[q * 4 + 0]); sq.y = f2bf(o1[q * 4 + 1]);
                sq.z = f2bf(o1[q * 4 + 2]); sq.w = f2bf(o1[q * 4 + 3]);
                *(short4*)(rowp + 16 + 12 * s + q * 4) = sq;
            }
            if (s == 0) atomicAdd(&counts_i[srcv], 1);
        } else {
            float* row = summed + (size_t)srcv * 40;
            #pragma unroll
            for (int i = 0; i < 4; ++i) {
                atomicAdd(row + i + 4 * s,     ALPHA0f * acc0[i]);
                atomicAdd(row + 8 + i + 4 * s, ALPHA0f * acc0[4 + i]);
            }
            #pragma unroll
            for (int q = 0; q < 12; ++q)
                atomicAdd(row + 16 + 12 * s + q, o1[q]);
            if (s == 0) atomicAdd(&counts[srcv], 1.0f);
        }
    }
}

extern "C" __global__ __launch_bounds__(256)
void scanA_kernel(const int* __restrict__ counts_i, int* __restrict__ offsets,
                  int* __restrict__ bsums)
{
    __shared__ int sm[256];
    int t = threadIdx.x, id = blockIdx.x * 256 + t;
    int c = (id < NNODES) ? counts_i[id] : 0;
    sm[t] = c; __syncthreads();
    #pragma unroll
    for (int off = 1; off < 256; off <<= 1) {
        int v = (t >= off) ? sm[t - off] : 0;
        __syncthreads();
        sm[t] += v;
        __syncthreads();
    }
    if (id < NNODES) offsets[id] = sm[t] - c;
    if (t == 255) bsums[blockIdx.x] = sm[255];
}

extern "C" __global__ __launch_bounds__(256)
void scanB_kernel(int* __restrict__ bsums, int nblocks)
{
    __shared__ int sm[256];
    int t = threadIdx.x;
    int c = (t < nblocks) ? bsums[t] : 0;
    sm[t] = c; __syncthreads();
    #pragma unroll
    for (int off = 1; off < 256; off <<= 1) {
        int v = (t >= off) ? sm[t - off] : 0;
        __syncthreads();
        sm[t] += v;
        __syncthreads();
    }
    if (t < nblocks) bsums[t] = sm[t] - c;
}

extern "C" __global__ __launch_bounds__(256)
void scanC_kernel(int* __restrict__ offsets, const int* __restrict__ bsums,
                  int* __restrict__ cursor)
{
    int id = blockIdx.x * 256 + threadIdx.x;
    if (id < NNODES) {
        int o = offsets[id] + bsums[id >> 8];
        offsets[id] = o;
        cursor[id] = o;
    }
}

extern "C" __global__ __launch_bounds__(256)
void scatter_kernel(const int* __restrict__ edge_index, int* __restrict__ cursor,
                    int* __restrict__ csr)
{
    int e = blockIdx.x * 256 + threadIdx.x;
    if (e < NEDGES) {
        int src = edge_index[e];
        int pos = atomicAdd(&cursor[src], 1);
        csr[pos] = e;
    }
}

// segmented mean + residual; one wave per node; tp rows = single 128-B lines (bf16)
extern "C" __global__ __launch_bounds__(256)
void gather_kernel(const unsigned short* __restrict__ tp, const int* __restrict__ offsets,
                   const int* __restrict__ csr, const float* __restrict__ node_attr,
                   float* __restrict__ out)
{
    int gw = (blockIdx.x * 256 + threadIdx.x) >> 6;
    int lane = threadIdx.x & 63;
    int nwaves = (gridDim.x * 256) >> 6;
    for (int n = gw; n < NNODES; n += nwaves) {
        int start = offsets[n];
        int end = (n + 1 < NNODES) ? offsets[n + 1] : NEDGES;
        float a0 = 0.f, a1 = 0.f, a2 = 0.f, a3 = 0.f;
        int i = start;
        for (; i + 8 <= end; i += 8) {
            int i0 = csr[i],     i1 = csr[i + 1], i2 = csr[i + 2], i3 = csr[i + 3];
            int i4 = csr[i + 4], i5 = csr[i + 5], i6 = csr[i + 6], i7 = csr[i + 7];
            if (lane < 40) {
                a0 += bf2f(tp[(size_t)i0 * TPROW + lane]);
                a1 += bf2f(tp[(size_t)i1 * TPROW + lane]);
                a2 += bf2f(tp[(size_t)i2 * TPROW + lane]);
                a3 += bf2f(tp[(size_t)i3 * TPROW + lane]);
                a0 += bf2f(tp[(size_t)i4 * TPROW + lane]);
                a1 += bf2f(tp[(size_t)i5 * TPROW + lane]);
                a2 += bf2f(tp[(size_t)i6 * TPROW + lane]);
                a3 += bf2f(tp[(size_t)i7 * TPROW + lane]);
            }
        }
        for (; i + 2 <= end; i += 2) {
            int i0 = csr[i], i1 = csr[i + 1];
            if (lane < 40) {
                a0 += bf2f(tp[(size_t)i0 * TPROW + lane]);
                a1 += bf2f(tp[(size_t)i1 * TPROW + lane]);
            }
        }
        if (i < end) {
            int i0 = csr[i];
            if (lane < 40) a0 += bf2f(tp[(size_t)i0 * TPROW + lane]);
        }
        if (lane < 40) {
            float deg = (float)(end - start);
            out[(size_t)n * 40 + lane] =
                ((a0 + a1) + (a2 + a3)) / fmaxf(deg, 1.0f) + node_attr[(size_t)n * 40 + lane];
        }
    }
}

extern "C" __global__ __launch_bounds__(256)
void finalize_kernel(const float* __restrict__ summed,
                     const float* __restrict__ counts,
                     const float* __restrict__ node_attr,
                     float* __restrict__ out)
{
    int idx = blockIdx.x * 256 + threadIdx.x;
    if (idx < NNODES * 40) {
        int n = idx / 40;
        float c = fmaxf(counts[n], 1.0f);
        out[idx] = summed[idx] / c + node_attr[idx];
    }
}

extern "C" void kernel_launch(void* const* d_in, const int* in_sizes, int n_in,
                              void* d_out, int out_size, void* d_ws, size_t ws_size,
                              hipStream_t stream)
{
    const float* node_attr  = (const float*)d_in[0];
    const int*   edge_index = (const int*)  d_in[1];
    const float* edge_attr  = (const float*)d_in[2];
    const float* edge_sh    = (const float*)d_in[3];
    const float* w1 = (const float*)d_in[4];
    const float* b1 = (const float*)d_in[5];
    const float* w2 = (const float*)d_in[6];
    const float* b2 = (const float*)d_in[7];
    float* out = (float*)d_out;

    const int SCAN_BLOCKS = (NNODES + 255) / 256;   // 196
    const int EDGE_BLOCKS = (NEDGES + 255) / 256;   // 1563
    const size_t NEED = (size_t)NEDGES * TPROW * 2 +
                        ((size_t)3 * NNODES + NEDGES + 256) * 4;

    if (ws_size >= NEED) {
        unsigned short* tp = (unsigned short*)d_ws;          // NEDGES*64 bf16 (128-B rows)
        int* counts_i = (int*)(tp + (size_t)NEDGES * TPROW); // NNODES
        int* offsets  = counts_i + NNODES;                   // NNODES
        int* cursor   = offsets + NNODES;                    // NNODES
        int* csr      = cursor + NNODES;                     // NEDGES
        int* bsums    = csr + NEDGES;                        // 256

        hipMemsetAsync(counts_i, 0, (size_t)NNODES * 4, stream);

        hipLaunchKernelGGL((tp_mfma_kernel<1>), dim3(512), dim3(512), 0, stream,
                           node_attr, edge_index, edge_attr, edge_sh, w1, b1, w2, b2,
                           tp, counts_i, (float*)nullptr, (float*)nullptr);

        hipLaunchKernelGGL(scanA_kernel, dim3(SCAN_BLOCKS), dim3(256), 0, stream,
                           counts_i, offsets, bsums);
        hipLaunchKernelGGL(scanB_kernel, dim3(1), dim3(256), 0, stream,
                           bsums, SCAN_BLOCKS);
        hipLaunchKernelGGL(scanC_kernel, dim3(SCAN_BLOCKS), dim3(256), 0, stream,
                           offsets, bsums, cursor);
        hipLaunchKernelGGL(scatter_kernel, dim3(EDGE_BLOCKS), dim3(256), 0, stream,
                           edge_index, cursor, csr);
        hipLaunchKernelGGL(gather_kernel, dim3(2048), dim3(256), 0, stream,
                           tp, offsets, csr, node_attr, out);
    } else {
        float* summed = (float*)d_ws;
        float* counts = summed + (size_t)NNODES * 40;
        hipMemsetAsync(d_ws, 0, (size_t)(NNODES * 40 + NNODES) * sizeof(float), stream);
        hipLaunchKernelGGL((tp_mfma_kernel<0>), dim3(512), dim3(512), 0, stream,
                           node_attr, edge_index, edge_attr, edge_sh, w1, b1, w2, b2,
                           (unsigned short*)nullptr, (int*)nullptr, summed, counts);
        int fblk = (NNODES * 40 + 255) / 256;
        hipLaunchKernelGGL(finalize_kernel, dim3(fblk), dim3(256), 0, stream,
                           summed, counts, node_attr, out);
    }
}